// Round 3
// baseline (128.707 us; speedup 1.0000x reference)
//
#include <hip/hip_runtime.h>
#include <math.h>

#define FF 2048

typedef __attribute__((ext_vector_type(8))) short short8;
typedef __attribute__((ext_vector_type(4))) float floatx4;

// ws float offsets. Split-K: S/H/sel/mem=8, logits=16.
#define OFF_SPART 0                      // [8][64][1000]
#define OFF_HPART 512000                 // [8][64][1000]
#define OFF_SELP  1024000                // [8][64][2048]
#define OFF_MEMP  2072576                // [8][64][2048]
#define OFF_LOGP  3121152                // [16][64][1000]
#define OFF_V     4145152                // [64][1024] softmax result (padded)
#define OFF_FEAT  4210688                // [64][2048]
#define OFF_CN2   4341760                // [1000]
#define OFF_WINV  4342760                // [1000]
#define OFF_XN2   4343760                // [64]
#define OFF_REACH 4343824                // [64]
#define OFF_NRM2P 4343888                // [64][8]

#define TP 40   // LDS tile pitch in shorts (mem kernel only)

__device__ __forceinline__ void split2(float f, ushort& h, ushort& l) {
  unsigned u = __float_as_uint(f);
  float r = f - __uint_as_float(u & 0xffff0000u);
  h = (ushort)(u >> 16);
  l = (ushort)(__float_as_uint(r) >> 16);
}

__device__ __forceinline__ void cvt8(const float4& a, const float4& b, short8& hi, short8& lo) {
  const float* f0 = (const float*)&a;
  const float* f1 = (const float*)&b;
  short8 h, l;
#pragma unroll
  for (int j = 0; j < 4; ++j) {
    ushort hh, ll;
    split2(f0[j], hh, ll);
    h[j] = (short)hh; l[j] = (short)ll;
    split2(f1[j], hh, ll);
    h[j + 4] = (short)hh; l[j + 4] = (short)ll;
  }
  hi = h; lo = l;
}

#define MFMA(a, b, c) __builtin_amdgcn_mfma_f32_16x16x32_bf16(a, b, c, 0, 0, 0)

__device__ __forceinline__ void mfma_step(const short8 (&ah)[2], const short8 (&al)[2],
                                          const short8 (&bh)[2], const short8 (&bl)[2],
                                          floatx4 (&acc)[2][2]) {
#pragma unroll
  for (int j = 0; j < 2; ++j)
#pragma unroll
    for (int i = 0; i < 2; ++i) {
      acc[i][j] = MFMA(ah[i], bh[j], acc[i][j]);
      acc[i][j] = MFMA(ah[i], bl[j], acc[i][j]);
      acc[i][j] = MFMA(al[i], bh[j], acc[i][j]);
    }
}

// LDS-free, barrier-free direct-to-register GEMM for row-major-K A and B (x@W^T shape).
// Wave computes a 32x32 quadrant of the block's 64x64 tile. Depth-1 reg prefetch.
template<int NSTEPS>
__device__ __forceinline__ void gemm_direct(
    const float* __restrict__ A, int ldA,
    const float* __restrict__ B, int ldB,
    int n0, int nB, int kbase,
    int ln15, int kq, int mh, int nh,
    floatx4 (&acc)[2][2]) {
  const float* pa[2];
  const float* pb[2];
  bool okb[2];
#pragma unroll
  for (int i = 0; i < 2; ++i) {
    int ra = (mh * 2 + i) * 16 + ln15;
    pa[i] = A + (size_t)ra * ldA + kbase + kq;
    int rb = n0 + (nh * 2 + i) * 16 + ln15;
    okb[i] = rb < nB;
    pb[i] = B + (size_t)rb * ldB + kbase + kq;
  }
  float4 ca[2][2], cb[2][2], na[2][2], nb[2][2];
#pragma unroll
  for (int i = 0; i < 2; ++i) {
    ca[i][0] = *(const float4*)(pa[i]);
    ca[i][1] = *(const float4*)(pa[i] + 4);
    cb[i][0] = make_float4(0.f, 0.f, 0.f, 0.f); cb[i][1] = cb[i][0];
    if (okb[i]) { cb[i][0] = *(const float4*)(pb[i]); cb[i][1] = *(const float4*)(pb[i] + 4); }
  }
#pragma unroll
  for (int s = 0; s < NSTEPS; ++s) {
    if (s + 1 < NSTEPS) {
      int off = (s + 1) * 32;
#pragma unroll
      for (int i = 0; i < 2; ++i) {
        na[i][0] = *(const float4*)(pa[i] + off);
        na[i][1] = *(const float4*)(pa[i] + off + 4);
        nb[i][0] = make_float4(0.f, 0.f, 0.f, 0.f); nb[i][1] = nb[i][0];
        if (okb[i]) { nb[i][0] = *(const float4*)(pb[i] + off); nb[i][1] = *(const float4*)(pb[i] + off + 4); }
      }
    }
    short8 ah[2], al[2], bh[2], bl[2];
#pragma unroll
    for (int i = 0; i < 2; ++i) {
      cvt8(ca[i][0], ca[i][1], ah[i], al[i]);
      cvt8(cb[i][0], cb[i][1], bh[i], bl[i]);
    }
    mfma_step(ah, al, bh, bl, acc);
    if (s + 1 < NSTEPS) {
#pragma unroll
      for (int i = 0; i < 2; ++i) {
        ca[i][0] = na[i][0]; ca[i][1] = na[i][1];
        cb[i][0] = nb[i][0]; cb[i][1] = nb[i][1];
      }
    }
  }
}

// ---- LDS helpers for the mem kernel only (B needs transpose) ----
struct R2 { float4 a, b; };

__device__ __forceinline__ void load_bt(const float* __restrict__ M, int ldK, int rowBase,
                                        int nrows, int k0, R2& s, int t) {
  int r = t >> 2, q = t & 3;
  int grow = rowBase + r;
  const float* src = M + (size_t)grow * ldK + k0 + q * 8;
  s.a = make_float4(0.f, 0.f, 0.f, 0.f);
  s.b = s.a;
  if (grow < nrows) {
    s.a = *(const float4*)src;
    s.b = *(const float4*)(src + 4);
  }
}

__device__ __forceinline__ void store_bt(const R2& s, ushort* __restrict__ hi,
                                         ushort* __restrict__ lo, int t) {
  int r = t >> 2, q = t & 3;
#pragma unroll
  for (int h = 0; h < 2; ++h) {
    const float4& v = h ? s.b : s.a;
    ushort4 hv, lv;
    split2(v.x, hv.x, lv.x); split2(v.y, hv.y, lv.y);
    split2(v.z, hv.z, lv.z); split2(v.w, hv.w, lv.w);
    int base = r * TP + q * 8 + h * 4;
    *(ushort4*)(hi + base) = hv;
    *(ushort4*)(lo + base) = lv;
  }
}

__device__ __forceinline__ void load_tr(const float* __restrict__ M, int ldN, int k0, int kmax,
                                        int n0, R2& s, int t) {
  int kk = t >> 3, c8 = (t & 7) * 8;
  int gk = k0 + kk;
  const float* src = M + (size_t)gk * ldN + n0 + c8;
  s.a = make_float4(0.f, 0.f, 0.f, 0.f);
  s.b = s.a;
  if (gk < kmax) {
    s.a = *(const float4*)src;
    s.b = *(const float4*)(src + 4);
  }
}

__device__ __forceinline__ void store_tr(const R2& s, ushort* __restrict__ hi,
                                         ushort* __restrict__ lo, int t) {
  int kk = t >> 3, c8 = (t & 7) * 8;
#pragma unroll
  for (int j = 0; j < 8; ++j) {
    float f = (j < 4) ? ((const float*)&s.a)[j] : ((const float*)&s.b)[j - 4];
    ushort h, l;
    split2(f, h, l);
    hi[(c8 + j) * TP + kk] = h;
    lo[(c8 + j) * TP + kk] = l;
  }
}

__device__ __forceinline__ void mfma_tile(const ushort* __restrict__ Ah, const ushort* __restrict__ Al,
                                          const ushort* __restrict__ Bh, const ushort* __restrict__ Bl,
                                          int ln15, int q8, int mh, int nh, floatx4 (&acc)[2][2]) {
  short8 ah[2], al[2];
#pragma unroll
  for (int i = 0; i < 2; ++i) {
    int row = (mh * 2 + i) * 16 + ln15;
    ah[i] = *(const short8*)(Ah + row * TP + q8);
    al[i] = *(const short8*)(Al + row * TP + q8);
  }
#pragma unroll
  for (int j = 0; j < 2; ++j) {
    int brow = (nh * 2 + j) * 16 + ln15;
    short8 bh = *(const short8*)(Bh + brow * TP + q8);
    short8 bl = *(const short8*)(Bl + brow * TP + q8);
#pragma unroll
    for (int i = 0; i < 2; ++i) {
      acc[i][j] = MFMA(ah[i], bh, acc[i][j]);
      acc[i][j] = MFMA(ah[i], bl, acc[i][j]);
      acc[i][j] = MFMA(al[i], bh, acc[i][j]);
    }
  }
}

// ================= Kernel 1: norms + S/H/sel GEMMs, all barrier-free =================
// 512 blocks: [0,128)=S, [128,256)=H (16 tiles x 8 splits), [256,512)=sel (32 x 8).
__global__ __launch_bounds__(256) void k1_gemm1(
    const float* __restrict__ x, const float* __restrict__ cent,
    const float* __restrict__ whall, const float* __restrict__ wsel,
    const float* __restrict__ wcos, float* __restrict__ ws) {
  int bx = blockIdx.x, t = threadIdx.x;
  int lane = t & 63, w = t >> 6;
  int ln15 = t & 15, lq = (t >> 4) & 3, kq = lq * 8;
  int mh = w & 1, nh = w >> 1;

  // ---- norms: |cent_r|^2, 1/|wcos_r|, |x_b|^2 ----
  for (int r = bx * 4 + w; r < 2064; r += 2048) {
    const float* src = (r < 1000) ? cent + (size_t)r * FF
                     : (r < 2000) ? wcos + (size_t)(r - 1000) * FF
                                  : x + (size_t)(r - 2000) * FF;
    float s = 0.f;
#pragma unroll
    for (int i = 0; i < 8; ++i) {
      float4 v = *(const float4*)(src + i * 256 + lane * 4);
      s += v.x * v.x + v.y * v.y + v.z * v.z + v.w * v.w;
    }
#pragma unroll
    for (int off = 32; off > 0; off >>= 1) s += __shfl_down(s, off, 64);
    if (lane == 0) {
      if (r < 1000) ws[OFF_CN2 + r] = s;
      else if (r < 2000) ws[OFF_WINV + (r - 1000)] = 1.f / sqrtf(s);
      else ws[OFF_XN2 + (r - 2000)] = s;
    }
  }

  floatx4 acc[2][2];
#pragma unroll
  for (int i = 0; i < 2; ++i)
#pragma unroll
    for (int j = 0; j < 2; ++j) acc[i][j] = (floatx4){0.f, 0.f, 0.f, 0.f};

  if (bx < 256) {
    int mat = bx >> 7;             // 0=S, 1=H
    int b2 = bx & 127;
    int tile = b2 & 15, ks = b2 >> 4;
    int n0 = tile * 64;
    const float* Bm = mat ? whall : cent;
    gemm_direct<8>(x, FF, Bm, FF, n0, 1000, ks * 256, ln15, kq, mh, nh, acc);
    float* outp = ws + (mat ? OFF_HPART : OFF_SPART) + (size_t)ks * 64000;
#pragma unroll
    for (int i = 0; i < 2; ++i)
#pragma unroll
      for (int j = 0; j < 2; ++j) {
        int gn = n0 + (nh * 2 + j) * 16 + ln15;
        if (gn < 1000) {
#pragma unroll
          for (int r = 0; r < 4; ++r) {
            int gm = (mh * 2 + i) * 16 + lq * 4 + r;
            outp[gm * 1000 + gn] = acc[i][j][r];
          }
        }
      }
  } else {
    int b2 = bx - 256;
    int tile = b2 & 31, ks = b2 >> 5;
    int n0 = tile * 64;
    gemm_direct<8>(x, FF, wsel, FF, n0, 2048, ks * 256, ln15, kq, mh, nh, acc);
    float* selp = ws + OFF_SELP + (size_t)ks * 131072;
#pragma unroll
    for (int i = 0; i < 2; ++i)
#pragma unroll
      for (int j = 0; j < 2; ++j) {
        int gn = n0 + (nh * 2 + j) * 16 + ln15;
#pragma unroll
        for (int r = 0; r < 4; ++r) {
          int gm = (mh * 2 + i) * 16 + lq * 4 + r;
          selp[gm * 2048 + gn] = acc[i][j][r];
        }
      }
  }
}

// ================= Kernel 2: reduce partials, min-dist + softmax -> V, reach =========
__global__ __launch_bounds__(256) void k2_softmax(const float* __restrict__ bhall,
                                                  float* __restrict__ ws) {
  __shared__ float hrow[1000];
  __shared__ float red[256];
  int b = blockIdx.x, t = threadIdx.x;
  float xn = ws[OFF_XN2 + b];
  float lmin = 3.0e38f, lmax = -3.0e38f;
  if (t < 250) {
    int c0 = t * 4;
    floatx4 S = {0.f, 0.f, 0.f, 0.f}, H = {0.f, 0.f, 0.f, 0.f};
#pragma unroll
    for (int ks = 0; ks < 8; ++ks) {
      floatx4 sv = *(const floatx4*)(ws + OFF_SPART + (size_t)ks * 64000 + b * 1000 + c0);
      floatx4 hv = *(const floatx4*)(ws + OFF_HPART + (size_t)ks * 64000 + b * 1000 + c0);
      S += sv; H += hv;
    }
    floatx4 bh = *(const floatx4*)(bhall + c0);
    floatx4 cn = *(const floatx4*)(ws + OFF_CN2 + c0);
#pragma unroll
    for (int j = 0; j < 4; ++j) {
      float Hf = H[j] + bh[j];
      hrow[c0 + j] = Hf;
      float d2 = xn - 2.f * S[j] + cn[j];
      lmin = fminf(lmin, d2);
      lmax = fmaxf(lmax, Hf);
    }
  }
  red[t] = lmin; __syncthreads();
  for (int s = 128; s > 0; s >>= 1) { if (t < s) red[t] = fminf(red[t], red[t + s]); __syncthreads(); }
  float bmin = red[0]; __syncthreads();
  red[t] = lmax; __syncthreads();
  for (int s = 128; s > 0; s >>= 1) { if (t < s) red[t] = fmaxf(red[t], red[t + s]); __syncthreads(); }
  float bmax = red[0]; __syncthreads();
  float lsum = 0.f;
  float e4[4] = {0.f, 0.f, 0.f, 0.f};
  if (t < 250) {
#pragma unroll
    for (int j = 0; j < 4; ++j) {
      e4[j] = expf(hrow[t * 4 + j] - bmax);
      lsum += e4[j];
    }
  }
  red[t] = lsum; __syncthreads();
  for (int s = 128; s > 0; s >>= 1) { if (t < s) red[t] += red[t + s]; __syncthreads(); }
  float inv = 1.f / red[0];
  if (t < 250)
    *(floatx4*)(ws + OFF_V + b * 1024 + t * 4) =
        (floatx4){e4[0] * inv, e4[1] * inv, e4[2] * inv, e4[3] * inv};
  if (t == 250) {  // pad V[1000..1023] so mem-GEMM loads blindly
#pragma unroll
    for (int j = 0; j < 24; ++j) ws[OFF_V + b * 1024 + 1000 + j] = 0.f;
  }
  if (t == 0) ws[OFF_REACH + b] = 10.f / sqrtf(bmin);
}

// ================= Kernel 3: mem = V@cent (K=1000, 32 tiles x 8 splits, LDS path) ====
__global__ __launch_bounds__(256) void k3_mem(const float* __restrict__ cent,
                                              float* __restrict__ ws) {
  __shared__ __align__(16) ushort u_lds[4 * 64 * TP];
  ushort* Ah = u_lds;
  ushort* Al = u_lds + 64 * TP;
  ushort* Bh = u_lds + 2 * 64 * TP;
  ushort* Bl = u_lds + 3 * 64 * TP;
  int bx = blockIdx.x, t = threadIdx.x;
  int ln15 = t & 15, lq = (t >> 4) & 3, q8 = lq * 8;
  int w = t >> 6, mh = w & 1, nh = w >> 1;
  int tile = bx & 31, ks = bx >> 5;
  int n0 = tile * 64;
  const float* V = ws + OFF_V;

  floatx4 acc[2][2];
#pragma unroll
  for (int i = 0; i < 2; ++i)
#pragma unroll
    for (int j = 0; j < 2; ++j) acc[i][j] = (floatx4){0.f, 0.f, 0.f, 0.f};

  R2 rA[2], rB[2];
  load_bt(V, 1024, 0, 64, ks * 128,      rA[0], t);
  load_tr(cent, FF, ks * 128,      1000, n0, rB[0], t);
  load_bt(V, 1024, 0, 64, ks * 128 + 32, rA[1], t);
  load_tr(cent, FF, ks * 128 + 32, 1000, n0, rB[1], t);
#pragma unroll
  for (int kc = 0; kc < 4; ++kc) {
    __syncthreads();
    store_bt(rA[kc & 1], Ah, Al, t);
    store_tr(rB[kc & 1], Bh, Bl, t);
    if (kc + 2 < 4) {
      load_bt(V, 1024, 0, 64, ks * 128 + (kc + 2) * 32, rA[kc & 1], t);
      load_tr(cent, FF, ks * 128 + (kc + 2) * 32, 1000, n0, rB[kc & 1], t);
    }
    __syncthreads();
    mfma_tile(Ah, Al, Bh, Bl, ln15, q8, mh, nh, acc);
  }
  float* memp = ws + OFF_MEMP + (size_t)ks * 131072;
#pragma unroll
  for (int i = 0; i < 2; ++i)
#pragma unroll
    for (int j = 0; j < 2; ++j) {
      int gn = n0 + (nh * 2 + j) * 16 + ln15;
#pragma unroll
      for (int r = 0; r < 4; ++r) {
        int gm = (mh * 2 + i) * 16 + lq * 4 + r;
        memp[gm * 2048 + gn] = acc[i][j][r];
      }
    }
}

// ================= Kernel 4: fuse. 64 rows x 8 chunks, one wave each =================
__global__ __launch_bounds__(64) void k4_fuse(const float* __restrict__ x,
                                              const float* __restrict__ bsel,
                                              float* __restrict__ ws, float* __restrict__ out) {
  int bx = blockIdx.x, t = threadIdx.x;
  int row = bx >> 3, ch = bx & 7;
  int f = ch * 256 + t * 4;
  const float* selp = ws + OFF_SELP + (size_t)row * 2048 + f;
  const float* memp = ws + OFF_MEMP + (size_t)row * 2048 + f;
  floatx4 sp = {0.f, 0.f, 0.f, 0.f}, mm = {0.f, 0.f, 0.f, 0.f};
#pragma unroll
  for (int ks = 0; ks < 8; ++ks) {
    sp += *(const floatx4*)(selp + (size_t)ks * 131072);
    mm += *(const floatx4*)(memp + (size_t)ks * 131072);
  }
  float4 bs4 = *(const float4*)(bsel + f);
  float4 x4  = *(const float4*)(x + (size_t)row * 2048 + f);
  float rch = ws[OFF_REACH + row];
  float4 inf4;
  floatx4 ft4;
  float nrm2 = 0.f;
#pragma unroll
  for (int j = 0; j < 4; ++j) {
    float sel = tanhf(sp[j] + ((float*)&bs4)[j]);
    float inf = sel * mm[j];
    float ft = rch * (((float*)&x4)[j] + inf);
    ((float*)&inf4)[j] = inf;
    ft4[j] = ft;
    nrm2 += ft * ft;
  }
  *(float4*)(out + 64000 + (size_t)row * 2048 + f) = x4;     // direct_feature
  *(float4*)(out + 195072 + (size_t)row * 2048 + f) = inf4;  // infused_feature
  *(floatx4*)(ws + OFF_FEAT + (size_t)row * 2048 + f) = ft4;
#pragma unroll
  for (int off = 32; off > 0; off >>= 1) nrm2 += __shfl_down(nrm2, off, 64);
  if (t == 0) ws[OFF_NRM2P + row * 8 + ch] = nrm2;
}

// ================= Kernel 5: logp = feat@wcos^T (16 tiles x 16 splits, direct) =======
__global__ __launch_bounds__(256) void k5_logits(const float* __restrict__ wcos,
                                                 float* __restrict__ ws) {
  int bx = blockIdx.x, t = threadIdx.x;
  int tile = bx & 15, ks = bx >> 4;   // ks in [0,16)
  int n0 = tile * 64;
  int ln15 = t & 15, lq = (t >> 4) & 3, kq = lq * 8;
  int w = t >> 6, mh = w & 1, nh = w >> 1;
  const float* feat = ws + OFF_FEAT;

  floatx4 acc[2][2];
#pragma unroll
  for (int i = 0; i < 2; ++i)
#pragma unroll
    for (int j = 0; j < 2; ++j) acc[i][j] = (floatx4){0.f, 0.f, 0.f, 0.f};

  gemm_direct<4>(feat, FF, wcos, FF, n0, 1000, ks * 128, ln15, kq, mh, nh, acc);

  float* logp = ws + OFF_LOGP + (size_t)ks * 64000;
#pragma unroll
  for (int i = 0; i < 2; ++i)
#pragma unroll
    for (int j = 0; j < 2; ++j) {
      int gn = n0 + (nh * 2 + j) * 16 + ln15;
      if (gn < 1000) {
#pragma unroll
        for (int r = 0; r < 4; ++r) {
          int gm = (mh * 2 + i) * 16 + lq * 4 + r;
          logp[gm * 1000 + gn] = acc[i][j][r];
        }
      }
    }
}

// ================= Kernel 6: reduce 16 logit partials, apply cos-norm scales =========
__global__ __launch_bounds__(128) void k6_final(float* __restrict__ ws, float* __restrict__ out) {
  int bx = blockIdx.x, t = threadIdx.x;
  int idx0 = (bx * 128 + t) * 4;
  const float* logp = ws + OFF_LOGP + idx0;
  floatx4 s = {0.f, 0.f, 0.f, 0.f};
#pragma unroll
  for (int ks = 0; ks < 16; ++ks)
    s += *(const floatx4*)(logp + (size_t)ks * 64000);
  floatx4 o4;
  int pb = -1;
  float sfac = 0.f;
#pragma unroll
  for (int j = 0; j < 4; ++j) {
    int idx = idx0 + j;
    int bb = idx / 1000;
    int cc = idx - bb * 1000;
    if (bb != pb) {
      float n2 = 0.f;
#pragma unroll
      for (int q = 0; q < 8; ++q) n2 += ws[OFF_NRM2P + bb * 8 + q];
      sfac = 16.f / (1.f + sqrtf(n2));
      pb = bb;
    }
    o4[j] = s[j] * sfac * ws[OFF_WINV + cc];
  }
  *(floatx4*)(out + idx0) = o4;
}

extern "C" void kernel_launch(void* const* d_in, const int* in_sizes, int n_in,
                              void* d_out, int out_size, void* d_ws, size_t ws_size,
                              hipStream_t stream) {
  const float* x     = (const float*)d_in[0];
  const float* cent  = (const float*)d_in[1];
  const float* whall = (const float*)d_in[2];
  const float* bhall = (const float*)d_in[3];
  const float* wsel  = (const float*)d_in[4];
  const float* bsel  = (const float*)d_in[5];
  const float* wcos  = (const float*)d_in[6];
  float* out = (float*)d_out;
  float* ws  = (float*)d_ws;

  hipLaunchKernelGGL(k1_gemm1,   dim3(512), dim3(256), 0, stream, x, cent, whall, wsel, wcos, ws);
  hipLaunchKernelGGL(k2_softmax, dim3(64),  dim3(256), 0, stream, bhall, ws);
  hipLaunchKernelGGL(k3_mem,     dim3(256), dim3(256), 0, stream, cent, ws);
  hipLaunchKernelGGL(k4_fuse,    dim3(512), dim3(64),  0, stream, x, bsel, ws, out);
  hipLaunchKernelGGL(k5_logits,  dim3(256), dim3(256), 0, stream, wcos, ws);
  hipLaunchKernelGGL(k6_final,   dim3(125), dim3(128), 0, stream, ws, out);
}